// Round 1
// baseline (408.258 us; speedup 1.0000x reference)
//
#include <hip/hip_runtime.h>
#include <cstdint>

#define NN 8192
#define NE 65536

// ---------- Threefry-2x32, 20 rounds, JAX-compatible ----------
__host__ __device__ inline void tf2x32(uint32_t k0, uint32_t k1,
                                       uint32_t x0, uint32_t x1,
                                       uint32_t& r0, uint32_t& r1) {
  uint32_t ks2 = k0 ^ k1 ^ 0x1BD11BDAu;
  x0 += k0; x1 += k1;
#define TF_ROT(x,d) (((x)<<(d))|((x)>>(32-(d))))
#define TF_R4(ra,rb,rc,rd) \
  x0+=x1; x1=TF_ROT(x1,ra); x1^=x0; \
  x0+=x1; x1=TF_ROT(x1,rb); x1^=x0; \
  x0+=x1; x1=TF_ROT(x1,rc); x1^=x0; \
  x0+=x1; x1=TF_ROT(x1,rd); x1^=x0;
  TF_R4(13,15,26,6)  x0+=k1;  x1+=ks2+1u;
  TF_R4(17,29,16,24) x0+=ks2; x1+=k0+2u;
  TF_R4(13,15,26,6)  x0+=k0;  x1+=k1+3u;
  TF_R4(17,29,16,24) x0+=k1;  x1+=ks2+4u;
  TF_R4(13,15,26,6)  x0+=ks2; x1+=k0+5u;
  r0=x0; r1=x1;
#undef TF_R4
#undef TF_ROT
}

// JAX partitionable 32-bit random bits: counter = (0, linear_index), bits = o0^o1
__device__ inline float gumbel32(uint32_t k0, uint32_t k1, uint32_t idx) {
  uint32_t a, b;
  tf2x32(k0, k1, 0u, idx, a, b);
  uint32_t bits = a ^ b;
  float f = __uint_as_float((bits >> 9) | 0x3f800000u) - 1.0f;
  float u = (f > 0.0f) ? f : 1.17549435e-38f;   // max(tiny, f*(1-tiny)+tiny) == this in f32
  return -logf(-logf(u));
}

__device__ inline float4 f4_axpy(float c, float4 a, float4 r) {
  r.x += c*a.x; r.y += c*a.y; r.z += c*a.z; r.w += c*a.w; return r;
}

// ---------- CSR build ----------
__global__ void k_zero(int* __restrict__ p, int n) {
  int i = blockIdx.x*blockDim.x + threadIdx.x;
  if (i < n) p[i] = 0;
}

__global__ void k_count(const int* __restrict__ ei, int* __restrict__ cnt) {
  int e = blockIdx.x*blockDim.x + threadIdx.x;
  if (e < NE) atomicAdd(&cnt[ei[e]], 1);
}

__global__ __launch_bounds__(1024) void k_scan(const int* __restrict__ cnt,
                                               int* __restrict__ row_ptr) {
  __shared__ int sums[1024];
  int t = threadIdx.x;
  int base = t * 8;
  int loc[8]; int run = 0;
  for (int i = 0; i < 8; i++) { loc[i] = run; run += cnt[base + i]; }
  sums[t] = run; __syncthreads();
  for (int off = 1; off < 1024; off <<= 1) {
    int v = sums[t];
    int add = (t >= off) ? sums[t - off] : 0;
    __syncthreads();
    sums[t] = v + add;
    __syncthreads();
  }
  int prev = (t == 0) ? 0 : sums[t - 1];
  for (int i = 0; i < 8; i++) row_ptr[base + i] = prev + loc[i];
  if (t == 1023) row_ptr[NN] = sums[1023];
}

__global__ void k_scatter(const int* __restrict__ ei, const int* __restrict__ row_ptr,
                          int* __restrict__ fill, int* __restrict__ csr_col) {
  int e = blockIdx.x*blockDim.x + threadIdx.x;
  if (e < NE) {
    int v = ei[e];
    int pos = row_ptr[v] + atomicAdd(&fill[v], 1);
    csr_col[pos] = ei[NE + e];
  }
}

__global__ void k_dinv0(const int* __restrict__ row_ptr, float* __restrict__ dinv0) {
  int v = blockIdx.x*blockDim.x + threadIdx.x;
  if (v < NN) dinv0[v] = 1.0f / sqrtf((float)(row_ptr[v+1] - row_ptr[v] + 1));
}

// ---------- A = -exp(A_log) ----------
__global__ void k_prepA(const float* __restrict__ alog, float* __restrict__ Amat) {
  int t = blockIdx.x*blockDim.x + threadIdx.x;
  if (t < 2048) Amat[t] = -expf(alog[t]);
}

// ---------- per-node precompute: xs, relu(res), delta, delta*xs, B, C ----------
__global__ __launch_bounds__(128) void k_nodeprep(
    const float* __restrict__ x, const float* __restrict__ ipw,
    const float* __restrict__ xpw, const float* __restrict__ dtw,
    float* __restrict__ xs, float* __restrict__ rres,
    float* __restrict__ delta, float* __restrict__ dxs,
    float* __restrict__ Bm, float* __restrict__ Cm) {
  __shared__ float sx[64];
  __shared__ float sxs[128];
  __shared__ float sdbl[4];
  int b = blockIdx.x, t = threadIdx.x;
  if (t < 64) sx[t] = x[b*64 + t];
  __syncthreads();
  float s1 = 0.f, s2 = 0.f;
  for (int k = 0; k < 64; k++) {
    float xv = sx[k];
    s1 += xv * ipw[k*256 + t];
    s2 += xv * ipw[k*256 + 128 + t];
  }
  float xsv = fmaxf(s1, 0.f);
  xs[b*128 + t] = xsv;
  rres[b*128 + t] = fmaxf(s2, 0.f);
  sxs[t] = xsv;
  __syncthreads();
  if (t < 36) {
    float acc = 0.f;
    for (int d = 0; d < 128; d++) acc += sxs[d] * xpw[d*36 + t];
    if (t < 4) sdbl[t] = acc;
    else if (t < 20) Bm[b*16 + (t-4)] = acc;
    else Cm[b*16 + (t-20)] = acc;
  }
  __syncthreads();
  float dt = 0.f;
  for (int r = 0; r < 4; r++) dt += sdbl[r] * dtw[r*128 + t];
  // softplus = logaddexp(dt, 0) = max(dt,0) + log1p(exp(-|dt|))
  float dv = fmaxf(dt, 0.f) + log1pf(expf(-fabsf(dt)));
  delta[b*128 + t] = dv;
  dxs[b*128 + t] = dv * xsv;
}

// ---------- state update + y: s' = exp(delta*A)*s + (delta*xs)*B ; y = <s',C> ----------
__global__ __launch_bounds__(256) void k_update(
    const float* __restrict__ delta, const float* __restrict__ dxs,
    const float* __restrict__ Bm, const float* __restrict__ Cm,
    const float* __restrict__ Amat,
    const float* __restrict__ s_old, float* __restrict__ s_new,
    float* __restrict__ yv, int first) {
  int t = blockIdx.x*blockDim.x + threadIdx.x;
  int b = t >> 7, d = t & 127;
  float de = delta[t], dx = dxs[t];
  const float4* Ar = (const float4*)(Amat + (d << 4));
  const float4* Br = (const float4*)(Bm + ((size_t)b << 4));
  const float4* Cr = (const float4*)(Cm + ((size_t)b << 4));
  const float4* So = (const float4*)(s_old + ((size_t)t << 4));
  float4* Sn = (float4*)(s_new + ((size_t)t << 4));
  float acc = 0.f;
#pragma unroll
  for (int q = 0; q < 4; q++) {
    float4 Bq = Br[q], Cq = Cr[q];
    float4 s;
    if (first) {
      s.x = dx*Bq.x; s.y = dx*Bq.y; s.z = dx*Bq.z; s.w = dx*Bq.w;
    } else {
      float4 a = Ar[q];
      float4 so = So[q];
      s.x = expf(de*a.x)*so.x + dx*Bq.x;
      s.y = expf(de*a.y)*so.y + dx*Bq.y;
      s.z = expf(de*a.z)*so.z + dx*Bq.z;
      s.w = expf(de*a.w)*so.w + dx*Bq.w;
    }
    acc += s.x*Cq.x + s.y*Cq.y + s.z*Cq.z + s.w*Cq.w;
    Sn[q] = s;
  }
  yv[t] = acc;
}

// ---------- layer-0 gumbel gates ----------
__global__ void k_gumbel(const float* __restrict__ yv,
                         const float* __restrict__ iaw, const float* __restrict__ iab,
                         const float* __restrict__ oaw, const float* __restrict__ oab,
                         uint32_t ki0, uint32_t ki1, uint32_t ko0, uint32_t ko1,
                         float* __restrict__ inp, float* __restrict__ outp) {
  int b = blockIdx.x*blockDim.x + threadIdx.x;
  if (b >= NN) return;
  const float* yr = yv + (size_t)b * 128;
  float li0 = 0.f, li1 = 0.f, lo0 = 0.f, lo1 = 0.f;
  for (int d = 0; d < 128; d++) {
    float yy = yr[d];
    li0 += yy * iaw[2*d];  li1 += yy * iaw[2*d+1];
    lo0 += yy * oaw[2*d];  lo1 += yy * oaw[2*d+1];
  }
  li0 += iab[0]; li1 += iab[1]; lo0 += oab[0]; lo1 += oab[1];
  uint32_t L0 = 2u*(uint32_t)b, L1 = L0 + 1u;
  float gi0 = gumbel32(ki0, ki1, L0), gi1 = gumbel32(ki0, ki1, L1);
  float go0 = gumbel32(ko0, ko1, L0), go1 = gumbel32(ko0, ko1, L1);
  // argmax over 2 logits, first index wins ties -> one-hot col 0
  inp[b]  = (li0 + gi0 >= li1 + gi1) ? 1.0f : 0.0f;
  outp[b] = (lo0 + go0 >= lo1 + go1) ? 1.0f : 0.0f;
}

// ---------- deg/dinv for gated adjacency ----------
__global__ void k_deg1(const int* __restrict__ row_ptr, const int* __restrict__ csr_col,
                       const float* __restrict__ inp, const float* __restrict__ outp,
                       float* __restrict__ dinv1) {
  int v = blockIdx.x*blockDim.x + threadIdx.x;
  if (v >= NN) return;
  float s = 0.f;
  int j1 = row_ptr[v+1];
  for (int j = row_ptr[v]; j < j1; j++) s += inp[csr_col[j]];
  dinv1[v] = 1.0f / sqrtf(outp[v]*s + 1.0f);
}

// ---------- spmm, uniform weights (layer 0) ----------
__global__ __launch_bounds__(256) void k_spmm0(
    const int* __restrict__ row_ptr, const int* __restrict__ csr_col,
    const float* __restrict__ dinv,
    const float* __restrict__ s_in, float* __restrict__ s_out) {
  int v = blockIdx.x, t = threadIdx.x;
  int j0 = row_ptr[v], j1 = row_ptr[v+1];
  float dv = dinv[v];
  float dw = dv * dv;
  const float4* self = (const float4*)(s_in + ((size_t)v << 11));
  float4 a0 = self[t], a1 = self[t + 256];
  a0.x *= dw; a0.y *= dw; a0.z *= dw; a0.w *= dw;
  a1.x *= dw; a1.y *= dw; a1.z *= dw; a1.w *= dw;
  for (int j = j0; j < j1; j++) {
    int c = csr_col[j];
    float coef = dv * dinv[c];
    const float4* nb = (const float4*)(s_in + ((size_t)c << 11));
    a0 = f4_axpy(coef, nb[t], a0);
    a1 = f4_axpy(coef, nb[t + 256], a1);
  }
  float4* op = (float4*)(s_out + ((size_t)v << 11));
  op[t] = a0; op[t + 256] = a1;
}

// ---------- spmm, gated 0/1 weights (layer 1) ----------
__global__ __launch_bounds__(256) void k_spmm1(
    const int* __restrict__ row_ptr, const int* __restrict__ csr_col,
    const float* __restrict__ dinv1,
    const float* __restrict__ inp, const float* __restrict__ outp,
    const float* __restrict__ s_in, float* __restrict__ s_out) {
  int v = blockIdx.x, t = threadIdx.x;
  float dv = dinv1[v];
  float dw = dv * dv;
  const float4* self = (const float4*)(s_in + ((size_t)v << 11));
  float4 a0 = self[t], a1 = self[t + 256];
  a0.x *= dw; a0.y *= dw; a0.z *= dw; a0.w *= dw;
  a1.x *= dw; a1.y *= dw; a1.z *= dw; a1.w *= dw;
  if (outp[v] != 0.f) {
    int j0 = row_ptr[v], j1 = row_ptr[v+1];
    for (int j = j0; j < j1; j++) {
      int c = csr_col[j];
      if (inp[c] != 0.f) {             // w = inp[c]*outp[v] is exactly 0 or 1
        float coef = dv * dinv1[c];
        const float4* nb = (const float4*)(s_in + ((size_t)c << 11));
        a0 = f4_axpy(coef, nb[t], a0);
        a1 = f4_axpy(coef, nb[t + 256], a1);
      }
    }
  }
  float4* op = (float4*)(s_out + ((size_t)v << 11));
  op[t] = a0; op[t + 256] = a1;
}

// ---------- epilogue: ((y + xs*D) * relu(res)) @ out_proj_w ----------
__global__ __launch_bounds__(64) void k_out(
    const float* __restrict__ yv, const float* __restrict__ xs,
    const float* __restrict__ rres, const float* __restrict__ Dv,
    const float* __restrict__ wout, float* __restrict__ out) {
  __shared__ float ty[128];
  int b = blockIdx.x, t = threadIdx.x;
  for (int i = t; i < 128; i += 64) {
    ty[i] = (yv[b*128 + i] + xs[b*128 + i]*Dv[i]) * rres[b*128 + i];
  }
  __syncthreads();
  float acc = 0.f;
  for (int d = 0; d < 128; d++) acc += ty[d] * wout[d*64 + t];
  out[b*64 + t] = acc;
}

extern "C" void kernel_launch(void* const* d_in, const int* in_sizes, int n_in,
                              void* d_out, int out_size, void* d_ws, size_t ws_size,
                              hipStream_t stream) {
  const float* x    = (const float*)d_in[0];
  const float* ipw  = (const float*)d_in[1];
  const float* xpw  = (const float*)d_in[2];
  const float* dtw  = (const float*)d_in[3];
  const float* alog = (const float*)d_in[4];
  const float* Dv   = (const float*)d_in[5];
  const float* wout = (const float*)d_in[6];
  const float* iaw  = (const float*)d_in[7];
  const float* iab  = (const float*)d_in[8];
  const float* oaw  = (const float*)d_in[9];
  const float* oab  = (const float*)d_in[10];
  const int*   ei   = (const int*)d_in[11];
  (void)in_sizes; (void)n_in; (void)out_size; (void)ws_size;

  float* W = (float*)d_ws;
  size_t o = 0;
  float* xs    = W + o; o += (size_t)NN*128;
  float* rres  = W + o; o += (size_t)NN*128;
  float* delta = W + o; o += (size_t)NN*128;
  float* dxs   = W + o; o += (size_t)NN*128;
  float* yv    = W + o; o += (size_t)NN*128;
  float* Bm    = W + o; o += (size_t)NN*16;
  float* Cm    = W + o; o += (size_t)NN*16;
  float* Amat  = W + o; o += 2048;
  float* dinv0 = W + o; o += NN;
  float* dinv1 = W + o; o += NN;
  float* inp   = W + o; o += NN;
  float* outp  = W + o; o += NN;
  float* stA   = W + o; o += (size_t)NN*2048;   // 16B-aligned (offset is multiple of 4 floats)
  float* stB   = W + o; o += (size_t)NN*2048;
  int* row_ptr = (int*)(W + o);
  int* cnt     = row_ptr + (NN + 1);
  int* fill    = cnt + NN;
  int* csr_col = fill + NN;

  // fold_in(key(42), 0) and fold_in(key(42), 1) -- host-side threefry
  uint32_t ki0, ki1, ko0, ko1;
  tf2x32(0u, 42u, 0u, 0u, ki0, ki1);
  tf2x32(0u, 42u, 0u, 1u, ko0, ko1);

  // CSR build (edge_index fixed per call)
  k_zero<<<(2*NN + 255)/256, 256, 0, stream>>>(cnt, 2*NN);
  k_count<<<NE/256, 256, 0, stream>>>(ei, cnt);
  k_scan<<<1, 1024, 0, stream>>>(cnt, row_ptr);
  k_scatter<<<NE/256, 256, 0, stream>>>(ei, row_ptr, fill, csr_col);
  k_dinv0<<<NN/256, 256, 0, stream>>>(row_ptr, dinv0);

  // per-node precompute
  k_prepA<<<8, 256, 0, stream>>>(alog, Amat);
  k_nodeprep<<<NN, 128, 0, stream>>>(x, ipw, xpw, dtw, xs, rres, delta, dxs, Bm, Cm);

  // layer 0: state = deltaB_u ; y0 ; gumbel gates ; dinv for gated adj ; spmm(uniform)
  k_update<<<(NN*128)/256, 256, 0, stream>>>(delta, dxs, Bm, Cm, Amat, stB, stA, yv, 1);
  k_gumbel<<<NN/256, 256, 0, stream>>>(yv, iaw, iab, oaw, oab, ki0, ki1, ko0, ko1, inp, outp);
  k_deg1<<<NN/256, 256, 0, stream>>>(row_ptr, csr_col, inp, outp, dinv1);
  k_spmm0<<<NN, 256, 0, stream>>>(row_ptr, csr_col, dinv0, stA, stB);

  // layer 1: state = dA*spmm0 + dBu ; spmm(gated)   (layer-1 gumbel is dead code)
  k_update<<<(NN*128)/256, 256, 0, stream>>>(delta, dxs, Bm, Cm, Amat, stB, stA, yv, 0);
  k_spmm1<<<NN, 256, 0, stream>>>(row_ptr, csr_col, dinv1, inp, outp, stA, stB);

  // layer 2: state = dA*spmm1 + dBu ; y2 -> output projection
  k_update<<<(NN*128)/256, 256, 0, stream>>>(delta, dxs, Bm, Cm, Amat, stB, stA, yv, 0);
  k_out<<<NN, 64, 0, stream>>>(yv, xs, rres, Dv, wout, (float*)d_out);
}

// Round 2
// 214.277 us; speedup vs baseline: 1.9053x; 1.9053x over previous
//
#include <hip/hip_runtime.h>
#include <cstdint>

#define NN 8192
#define NE 65536

// ---------- Threefry-2x32, 20 rounds, JAX-compatible ----------
__host__ __device__ inline void tf2x32(uint32_t k0, uint32_t k1,
                                       uint32_t x0, uint32_t x1,
                                       uint32_t& r0, uint32_t& r1) {
  uint32_t ks2 = k0 ^ k1 ^ 0x1BD11BDAu;
  x0 += k0; x1 += k1;
#define TF_ROT(x,d) (((x)<<(d))|((x)>>(32-(d))))
#define TF_R4(ra,rb,rc,rd) \
  x0+=x1; x1=TF_ROT(x1,ra); x1^=x0; \
  x0+=x1; x1=TF_ROT(x1,rb); x1^=x0; \
  x0+=x1; x1=TF_ROT(x1,rc); x1^=x0; \
  x0+=x1; x1=TF_ROT(x1,rd); x1^=x0;
  TF_R4(13,15,26,6)  x0+=k1;  x1+=ks2+1u;
  TF_R4(17,29,16,24) x0+=ks2; x1+=k0+2u;
  TF_R4(13,15,26,6)  x0+=k0;  x1+=k1+3u;
  TF_R4(17,29,16,24) x0+=k1;  x1+=ks2+4u;
  TF_R4(13,15,26,6)  x0+=ks2; x1+=k0+5u;
  r0=x0; r1=x1;
#undef TF_R4
#undef TF_ROT
}

// JAX partitionable 32-bit random bits: counter = (0, linear_index), bits = o0^o1
__device__ inline float gumbel32(uint32_t k0, uint32_t k1, uint32_t idx) {
  uint32_t a, b;
  tf2x32(k0, k1, 0u, idx, a, b);
  uint32_t bits = a ^ b;
  float f = __uint_as_float((bits >> 9) | 0x3f800000u) - 1.0f;
  float u = (f > 0.0f) ? f : 1.17549435e-38f;
  return -logf(-logf(u));
}

// ---------- CSR build ----------
__global__ void k_zero(int* __restrict__ p, int n) {
  int i = blockIdx.x*blockDim.x + threadIdx.x;
  if (i < n) p[i] = 0;
}

__global__ void k_count(const int* __restrict__ ei, int* __restrict__ cnt) {
  int e = blockIdx.x*blockDim.x + threadIdx.x;
  if (e < NE) atomicAdd(&cnt[ei[e]], 1);
}

__global__ __launch_bounds__(1024) void k_scan(const int* __restrict__ cnt,
                                               int* __restrict__ row_ptr) {
  __shared__ int sums[1024];
  int t = threadIdx.x;
  int base = t * 8;
  int loc[8]; int run = 0;
  for (int i = 0; i < 8; i++) { loc[i] = run; run += cnt[base + i]; }
  sums[t] = run; __syncthreads();
  for (int off = 1; off < 1024; off <<= 1) {
    int v = sums[t];
    int add = (t >= off) ? sums[t - off] : 0;
    __syncthreads();
    sums[t] = v + add;
    __syncthreads();
  }
  int prev = (t == 0) ? 0 : sums[t - 1];
  for (int i = 0; i < 8; i++) row_ptr[base + i] = prev + loc[i];
  if (t == 1023) row_ptr[NN] = sums[1023];
}

__global__ void k_scatter(const int* __restrict__ ei, const int* __restrict__ row_ptr,
                          int* __restrict__ fill, int* __restrict__ csr_col) {
  int e = blockIdx.x*blockDim.x + threadIdx.x;
  if (e < NE) {
    int v = ei[e];
    int pos = row_ptr[v] + atomicAdd(&fill[v], 1);
    csr_col[pos] = ei[NE + e];
  }
}

__global__ void k_dinv0(const int* __restrict__ row_ptr, float* __restrict__ dinv0) {
  int v = blockIdx.x*blockDim.x + threadIdx.x;
  if (v < NN) dinv0[v] = 1.0f / sqrtf((float)(row_ptr[v+1] - row_ptr[v] + 1));
}

// ---------- A = -exp(A_log) ----------
__global__ void k_prepA(const float* __restrict__ alog, float* __restrict__ Amat) {
  int t = blockIdx.x*blockDim.x + threadIdx.x;
  if (t < 2048) Amat[t] = -expf(alog[t]);
}

// ---------- per-node precompute + layer-0 gumbel gates ----------
// xs, relu(res), delta, delta*xs, B, C ; y0 = dxs * <B,C>  (rank-1) -> gates
__global__ __launch_bounds__(128) void k_nodeprep(
    const float* __restrict__ x, const float* __restrict__ ipw,
    const float* __restrict__ xpw, const float* __restrict__ dtw,
    const float* __restrict__ iaw, const float* __restrict__ iab,
    const float* __restrict__ oaw, const float* __restrict__ oab,
    uint32_t ki0, uint32_t ki1, uint32_t ko0, uint32_t ko1,
    float* __restrict__ xs, float* __restrict__ rres,
    float* __restrict__ delta, float* __restrict__ dxs,
    float* __restrict__ Bm, float* __restrict__ Cm,
    float* __restrict__ inp, float* __restrict__ outp) {
  __shared__ float sx[64];
  __shared__ float sxs[128];
  __shared__ float sdbl[4];
  __shared__ float sB[16], sC[16];
  __shared__ float4 swred[2];
  int b = blockIdx.x, t = threadIdx.x;
  if (t < 64) sx[t] = x[b*64 + t];
  __syncthreads();
  float s1 = 0.f, s2 = 0.f;
  for (int k = 0; k < 64; k++) {
    float xv = sx[k];
    s1 += xv * ipw[k*256 + t];
    s2 += xv * ipw[k*256 + 128 + t];
  }
  float xsv = fmaxf(s1, 0.f);
  xs[b*128 + t] = xsv;
  rres[b*128 + t] = fmaxf(s2, 0.f);
  sxs[t] = xsv;
  __syncthreads();
  if (t < 36) {
    float acc = 0.f;
    for (int d = 0; d < 128; d++) acc += sxs[d] * xpw[d*36 + t];
    if (t < 4) sdbl[t] = acc;
    else if (t < 20) { Bm[b*16 + (t-4)] = acc; sB[t-4] = acc; }
    else             { Cm[b*16 + (t-20)] = acc; sC[t-20] = acc; }
  }
  __syncthreads();
  float dt = 0.f;
  for (int r = 0; r < 4; r++) dt += sdbl[r] * dtw[r*128 + t];
  float dv = fmaxf(dt, 0.f) + log1pf(expf(-fabsf(dt)));  // softplus
  delta[b*128 + t] = dv;
  float dxv = dv * xsv;
  dxs[b*128 + t] = dxv;
  // gate logits: logit_j = BC * sum_d dxs[d]*w[d,j] + bias_j
  float4 pr;
  pr.x = dxv * iaw[2*t];   pr.y = dxv * iaw[2*t+1];
  pr.z = dxv * oaw[2*t];   pr.w = dxv * oaw[2*t+1];
  for (int off = 32; off >= 1; off >>= 1) {
    pr.x += __shfl_down(pr.x, off);
    pr.y += __shfl_down(pr.y, off);
    pr.z += __shfl_down(pr.z, off);
    pr.w += __shfl_down(pr.w, off);
  }
  int lane = t & 63, wid = t >> 6;
  if (lane == 0) swred[wid] = pr;
  __syncthreads();
  if (t == 0) {
    float4 q0 = swred[0], q1 = swred[1];
    float BC = 0.f;
    for (int n = 0; n < 16; n++) BC += sB[n] * sC[n];
    float li0 = BC*(q0.x+q1.x) + iab[0], li1 = BC*(q0.y+q1.y) + iab[1];
    float lo0 = BC*(q0.z+q1.z) + oab[0], lo1 = BC*(q0.w+q1.w) + oab[1];
    uint32_t L0 = 2u*(uint32_t)b, L1 = L0 + 1u;
    inp[b]  = (li0 + gumbel32(ki0, ki1, L0) >= li1 + gumbel32(ki0, ki1, L1)) ? 1.0f : 0.0f;
    outp[b] = (lo0 + gumbel32(ko0, ko1, L0) >= lo1 + gumbel32(ko0, ko1, L1)) ? 1.0f : 0.0f;
  }
}

// ---------- deg/dinv for gated adjacency ----------
__global__ void k_deg1(const int* __restrict__ row_ptr, const int* __restrict__ csr_col,
                       const float* __restrict__ inp, const float* __restrict__ outp,
                       float* __restrict__ dinv1) {
  int v = blockIdx.x*blockDim.x + threadIdx.x;
  if (v >= NN) return;
  float s = 0.f;
  int j1 = row_ptr[v+1];
  for (int j = row_ptr[v]; j < j1; j++) s += inp[csr_col[j]];
  dinv1[v] = 1.0f / sqrtf(outp[v]*s + 1.0f);
}

// ---------- fused spmm0 (rank-1 gather) + layer-1 update ----------
// flat0[v] = sum_c coef * dxs[c] (x) B[c]  + dw * dxs[v] (x) B[v]
// state1[v] = exp(delta[v]*A) * flat0[v] + dxs[v] (x) B[v]
__global__ __launch_bounds__(256) void k_spmm0f(
    const int* __restrict__ row_ptr, const int* __restrict__ csr_col,
    const float* __restrict__ dinv,
    const float* __restrict__ delta, const float* __restrict__ dxs,
    const float* __restrict__ Bm, const float* __restrict__ Amat,
    float* __restrict__ s_out) {
  int v = blockIdx.x, t = threadIdx.x;
  int d0 = t >> 2, d1 = d0 + 64, nb = t & 3;
  float dv = dinv[v];
  float4 Bv = ((const float4*)(Bm + ((size_t)v << 4)))[nb];
  float dx0 = dxs[v*128 + d0], dx1 = dxs[v*128 + d1];
  float dw = dv * dv;
  float c0 = dw * dx0, c1 = dw * dx1;
  float4 a0 = {c0*Bv.x, c0*Bv.y, c0*Bv.z, c0*Bv.w};
  float4 a1 = {c1*Bv.x, c1*Bv.y, c1*Bv.z, c1*Bv.w};
  int j0 = row_ptr[v], j1 = row_ptr[v+1];
  for (int j = j0; j < j1; j++) {
    int c = csr_col[j];
    float coef = dv * dinv[c];
    float4 Bc = ((const float4*)(Bm + ((size_t)c << 4)))[nb];
    float e0 = coef * dxs[c*128 + d0];
    float e1 = coef * dxs[c*128 + d1];
    a0.x += e0*Bc.x; a0.y += e0*Bc.y; a0.z += e0*Bc.z; a0.w += e0*Bc.w;
    a1.x += e1*Bc.x; a1.y += e1*Bc.y; a1.z += e1*Bc.z; a1.w += e1*Bc.w;
  }
  float de0 = delta[v*128 + d0], de1 = delta[v*128 + d1];
  float4 A0 = ((const float4*)(Amat + (d0 << 4)))[nb];
  float4 A1 = ((const float4*)(Amat + (d1 << 4)))[nb];
  float4 s0, s1;
  s0.x = expf(de0*A0.x)*a0.x + dx0*Bv.x;
  s0.y = expf(de0*A0.y)*a0.y + dx0*Bv.y;
  s0.z = expf(de0*A0.z)*a0.z + dx0*Bv.z;
  s0.w = expf(de0*A0.w)*a0.w + dx0*Bv.w;
  s1.x = expf(de1*A1.x)*a1.x + dx1*Bv.x;
  s1.y = expf(de1*A1.y)*a1.y + dx1*Bv.y;
  s1.z = expf(de1*A1.z)*a1.z + dx1*Bv.z;
  s1.w = expf(de1*A1.w)*a1.w + dx1*Bv.w;
  float4* op = (float4*)(s_out + ((size_t)v << 11));
  op[t] = s0; op[t + 256] = s1;
}

// ---------- fused spmm1 (gated) + layer-2 update + C-contraction ----------
// flat1[v] = gated spmm of state1 ; s2 = exp(delta*A)*flat1 + dxs (x) B ; y2 = <s2, C>
__global__ __launch_bounds__(256) void k_spmm1f(
    const int* __restrict__ row_ptr, const int* __restrict__ csr_col,
    const float* __restrict__ dinv1,
    const float* __restrict__ inp, const float* __restrict__ outp,
    const float* __restrict__ delta, const float* __restrict__ dxs,
    const float* __restrict__ Bm, const float* __restrict__ Cm,
    const float* __restrict__ Amat,
    const float* __restrict__ s_in, float* __restrict__ yv) {
  int v = blockIdx.x, t = threadIdx.x;
  int d0 = t >> 2, d1 = d0 + 64, nb = t & 3;
  float dv = dinv1[v];
  float dw = dv * dv;
  const float4* self = (const float4*)(s_in + ((size_t)v << 11));
  float4 a0 = self[t], a1 = self[t + 256];
  a0.x *= dw; a0.y *= dw; a0.z *= dw; a0.w *= dw;
  a1.x *= dw; a1.y *= dw; a1.z *= dw; a1.w *= dw;
  if (outp[v] != 0.f) {
    int j0 = row_ptr[v], j1 = row_ptr[v+1];
    for (int j = j0; j < j1; j++) {
      int c = csr_col[j];
      if (inp[c] != 0.f) {
        float coef = dv * dinv1[c];
        const float4* nbp = (const float4*)(s_in + ((size_t)c << 11));
        float4 n0 = nbp[t], n1 = nbp[t + 256];
        a0.x += coef*n0.x; a0.y += coef*n0.y; a0.z += coef*n0.z; a0.w += coef*n0.w;
        a1.x += coef*n1.x; a1.y += coef*n1.y; a1.z += coef*n1.z; a1.w += coef*n1.w;
      }
    }
  }
  float de0 = delta[v*128 + d0], de1 = delta[v*128 + d1];
  float dx0 = dxs[v*128 + d0],  dx1 = dxs[v*128 + d1];
  float4 Bv = ((const float4*)(Bm + ((size_t)v << 4)))[nb];
  float4 Cv = ((const float4*)(Cm + ((size_t)v << 4)))[nb];
  float4 A0 = ((const float4*)(Amat + (d0 << 4)))[nb];
  float4 A1 = ((const float4*)(Amat + (d1 << 4)))[nb];
  float y0p =
      (expf(de0*A0.x)*a0.x + dx0*Bv.x) * Cv.x +
      (expf(de0*A0.y)*a0.y + dx0*Bv.y) * Cv.y +
      (expf(de0*A0.z)*a0.z + dx0*Bv.z) * Cv.z +
      (expf(de0*A0.w)*a0.w + dx0*Bv.w) * Cv.w;
  float y1p =
      (expf(de1*A1.x)*a1.x + dx1*Bv.x) * Cv.x +
      (expf(de1*A1.y)*a1.y + dx1*Bv.y) * Cv.y +
      (expf(de1*A1.z)*a1.z + dx1*Bv.z) * Cv.z +
      (expf(de1*A1.w)*a1.w + dx1*Bv.w) * Cv.w;
  y0p += __shfl_xor(y0p, 1); y0p += __shfl_xor(y0p, 2);
  y1p += __shfl_xor(y1p, 1); y1p += __shfl_xor(y1p, 2);
  if (nb == 0) {
    yv[v*128 + d0] = y0p;
    yv[v*128 + d1] = y1p;
  }
}

// ---------- epilogue: ((y + xs*D) * relu(res)) @ out_proj_w ----------
__global__ __launch_bounds__(64) void k_out(
    const float* __restrict__ yv, const float* __restrict__ xs,
    const float* __restrict__ rres, const float* __restrict__ Dv,
    const float* __restrict__ wout, float* __restrict__ out) {
  __shared__ float ty[128];
  int b = blockIdx.x, t = threadIdx.x;
  for (int i = t; i < 128; i += 64) {
    ty[i] = (yv[b*128 + i] + xs[b*128 + i]*Dv[i]) * rres[b*128 + i];
  }
  __syncthreads();
  float acc = 0.f;
  for (int d = 0; d < 128; d++) acc += ty[d] * wout[d*64 + t];
  out[b*64 + t] = acc;
}

extern "C" void kernel_launch(void* const* d_in, const int* in_sizes, int n_in,
                              void* d_out, int out_size, void* d_ws, size_t ws_size,
                              hipStream_t stream) {
  const float* x    = (const float*)d_in[0];
  const float* ipw  = (const float*)d_in[1];
  const float* xpw  = (const float*)d_in[2];
  const float* dtw  = (const float*)d_in[3];
  const float* alog = (const float*)d_in[4];
  const float* Dv   = (const float*)d_in[5];
  const float* wout = (const float*)d_in[6];
  const float* iaw  = (const float*)d_in[7];
  const float* iab  = (const float*)d_in[8];
  const float* oaw  = (const float*)d_in[9];
  const float* oab  = (const float*)d_in[10];
  const int*   ei   = (const int*)d_in[11];
  (void)in_sizes; (void)n_in; (void)out_size; (void)ws_size;

  float* W = (float*)d_ws;
  size_t o = 0;
  float* xs    = W + o; o += (size_t)NN*128;
  float* rres  = W + o; o += (size_t)NN*128;
  float* delta = W + o; o += (size_t)NN*128;
  float* dxs   = W + o; o += (size_t)NN*128;
  float* yv    = W + o; o += (size_t)NN*128;
  float* Bm    = W + o; o += (size_t)NN*16;
  float* Cm    = W + o; o += (size_t)NN*16;
  float* Amat  = W + o; o += 2048;
  float* dinv0 = W + o; o += NN;
  float* dinv1 = W + o; o += NN;
  float* inp   = W + o; o += NN;
  float* outp  = W + o; o += NN;
  float* stA   = W + o; o += (size_t)NN*2048;   // state1, 64 MB
  int* row_ptr = (int*)(W + o);
  int* cnt     = row_ptr + (NN + 1);
  int* fill    = cnt + NN;
  int* csr_col = fill + NN;

  uint32_t ki0, ki1, ko0, ko1;
  tf2x32(0u, 42u, 0u, 0u, ki0, ki1);
  tf2x32(0u, 42u, 0u, 1u, ko0, ko1);

  // CSR build
  k_zero<<<(2*NN + 255)/256, 256, 0, stream>>>(cnt, 2*NN);
  k_count<<<NE/256, 256, 0, stream>>>(ei, cnt);
  k_scan<<<1, 1024, 0, stream>>>(cnt, row_ptr);
  k_scatter<<<NE/256, 256, 0, stream>>>(ei, row_ptr, fill, csr_col);
  k_dinv0<<<NN/256, 256, 0, stream>>>(row_ptr, dinv0);

  // per-node precompute + layer-0 gates (y0 is rank-1)
  k_prepA<<<8, 256, 0, stream>>>(alog, Amat);
  k_nodeprep<<<NN, 128, 0, stream>>>(x, ipw, xpw, dtw, iaw, iab, oaw, oab,
                                     ki0, ki1, ko0, ko1,
                                     xs, rres, delta, dxs, Bm, Cm, inp, outp);
  k_deg1<<<NN/256, 256, 0, stream>>>(row_ptr, csr_col, inp, outp, dinv1);

  // layer 0 spmm (rank-1 gather) fused with layer-1 state update -> state1
  k_spmm0f<<<NN, 256, 0, stream>>>(row_ptr, csr_col, dinv0, delta, dxs, Bm, Amat, stA);

  // layer 1 gated spmm fused with layer-2 update + C-contraction -> y2
  k_spmm1f<<<NN, 256, 0, stream>>>(row_ptr, csr_col, dinv1, inp, outp,
                                   delta, dxs, Bm, Cm, Amat, stA, yv);

  // output projection
  k_out<<<NN, 64, 0, stream>>>(yv, xs, rres, Dv, wout, (float*)d_out);
}

// Round 3
// 195.153 us; speedup vs baseline: 2.0920x; 1.0980x over previous
//
#include <hip/hip_runtime.h>
#include <cstdint>

#define NN 8192
#define NE 65536

// ---------- Threefry-2x32, 20 rounds, JAX-compatible ----------
__host__ __device__ inline void tf2x32(uint32_t k0, uint32_t k1,
                                       uint32_t x0, uint32_t x1,
                                       uint32_t& r0, uint32_t& r1) {
  uint32_t ks2 = k0 ^ k1 ^ 0x1BD11BDAu;
  x0 += k0; x1 += k1;
#define TF_ROT(x,d) (((x)<<(d))|((x)>>(32-(d))))
#define TF_R4(ra,rb,rc,rd) \
  x0+=x1; x1=TF_ROT(x1,ra); x1^=x0; \
  x0+=x1; x1=TF_ROT(x1,rb); x1^=x0; \
  x0+=x1; x1=TF_ROT(x1,rc); x1^=x0; \
  x0+=x1; x1=TF_ROT(x1,rd); x1^=x0;
  TF_R4(13,15,26,6)  x0+=k1;  x1+=ks2+1u;
  TF_R4(17,29,16,24) x0+=ks2; x1+=k0+2u;
  TF_R4(13,15,26,6)  x0+=k0;  x1+=k1+3u;
  TF_R4(17,29,16,24) x0+=k1;  x1+=ks2+4u;
  TF_R4(13,15,26,6)  x0+=ks2; x1+=k0+5u;
  r0=x0; r1=x1;
#undef TF_R4
#undef TF_ROT
}

__device__ inline float gumbel32(uint32_t k0, uint32_t k1, uint32_t idx) {
  uint32_t a, b;
  tf2x32(k0, k1, 0u, idx, a, b);
  uint32_t bits = a ^ b;
  float f = __uint_as_float((bits >> 9) | 0x3f800000u) - 1.0f;
  float u = (f > 0.0f) ? f : 1.17549435e-38f;
  return -logf(-logf(u));
}

// ---------- CSR build ----------
__global__ void k_zero(int* __restrict__ p, int n) {
  int i = blockIdx.x*blockDim.x + threadIdx.x;
  if (i < n) p[i] = 0;
}

__global__ void k_count(const int* __restrict__ ei, int* __restrict__ cnt) {
  int e = blockIdx.x*blockDim.x + threadIdx.x;
  if (e < NE) atomicAdd(&cnt[ei[e]], 1);
}

__global__ __launch_bounds__(1024) void k_scan(const int* __restrict__ cnt,
                                               int* __restrict__ row_ptr) {
  __shared__ int sums[1024];
  int t = threadIdx.x;
  int base = t * 8;
  int loc[8]; int run = 0;
  for (int i = 0; i < 8; i++) { loc[i] = run; run += cnt[base + i]; }
  sums[t] = run; __syncthreads();
  for (int off = 1; off < 1024; off <<= 1) {
    int v = sums[t];
    int add = (t >= off) ? sums[t - off] : 0;
    __syncthreads();
    sums[t] = v + add;
    __syncthreads();
  }
  int prev = (t == 0) ? 0 : sums[t - 1];
  for (int i = 0; i < 8; i++) row_ptr[base + i] = prev + loc[i];
  if (t == 1023) row_ptr[NN] = sums[1023];
}

__global__ void k_scatter(const int* __restrict__ ei, const int* __restrict__ row_ptr,
                          int* __restrict__ fill, int* __restrict__ csr_col) {
  int e = blockIdx.x*blockDim.x + threadIdx.x;
  if (e < NE) {
    int v = ei[e];
    int pos = row_ptr[v] + atomicAdd(&fill[v], 1);
    csr_col[pos] = ei[NE + e];
  }
}

__global__ void k_dinv0(const int* __restrict__ row_ptr, float* __restrict__ dinv0) {
  int v = blockIdx.x*blockDim.x + threadIdx.x;
  if (v < NN) dinv0[v] = 1.0f / sqrtf((float)(row_ptr[v+1] - row_ptr[v] + 1));
}

__global__ void k_prepA(const float* __restrict__ alog, float* __restrict__ Amat) {
  int t = blockIdx.x*blockDim.x + threadIdx.x;
  if (t < 2048) Amat[t] = -expf(alog[t]);
}

// ---------- per-node precompute + layer-0 gumbel gates ----------
__global__ __launch_bounds__(128) void k_nodeprep(
    const float* __restrict__ x, const float* __restrict__ ipw,
    const float* __restrict__ xpw, const float* __restrict__ dtw,
    const float* __restrict__ iaw, const float* __restrict__ iab,
    const float* __restrict__ oaw, const float* __restrict__ oab,
    uint32_t ki0, uint32_t ki1, uint32_t ko0, uint32_t ko1,
    float* __restrict__ xs, float* __restrict__ rres,
    float* __restrict__ delta, float* __restrict__ dxs,
    float* __restrict__ Bm, float* __restrict__ Cm,
    float* __restrict__ inp, float* __restrict__ outp) {
  __shared__ float sx[64];
  __shared__ float sxs[128];
  __shared__ float sdbl[4];
  __shared__ float sB[16], sC[16];
  __shared__ float4 swred[2];
  int b = blockIdx.x, t = threadIdx.x;
  if (t < 64) sx[t] = x[b*64 + t];
  __syncthreads();
  float s1 = 0.f, s2 = 0.f;
  for (int k = 0; k < 64; k++) {
    float xv = sx[k];
    s1 += xv * ipw[k*256 + t];
    s2 += xv * ipw[k*256 + 128 + t];
  }
  float xsv = fmaxf(s1, 0.f);
  xs[b*128 + t] = xsv;
  rres[b*128 + t] = fmaxf(s2, 0.f);
  sxs[t] = xsv;
  __syncthreads();
  if (t < 36) {
    float acc = 0.f;
    for (int d = 0; d < 128; d++) acc += sxs[d] * xpw[d*36 + t];
    if (t < 4) sdbl[t] = acc;
    else if (t < 20) { Bm[b*16 + (t-4)] = acc; sB[t-4] = acc; }
    else             { Cm[b*16 + (t-20)] = acc; sC[t-20] = acc; }
  }
  __syncthreads();
  float dt = 0.f;
  for (int r = 0; r < 4; r++) dt += sdbl[r] * dtw[r*128 + t];
  float dv = fmaxf(dt, 0.f) + log1pf(expf(-fabsf(dt)));  // softplus
  delta[b*128 + t] = dv;
  float dxv = dv * xsv;
  dxs[b*128 + t] = dxv;
  // gate logits: logit_j = BC * sum_d dxs[d]*w[d,j] + bias_j  (y0 is rank-1)
  float4 pr;
  pr.x = dxv * iaw[2*t];   pr.y = dxv * iaw[2*t+1];
  pr.z = dxv * oaw[2*t];   pr.w = dxv * oaw[2*t+1];
  for (int off = 32; off >= 1; off >>= 1) {
    pr.x += __shfl_down(pr.x, off);
    pr.y += __shfl_down(pr.y, off);
    pr.z += __shfl_down(pr.z, off);
    pr.w += __shfl_down(pr.w, off);
  }
  int lane = t & 63, wid = t >> 6;
  if (lane == 0) swred[wid] = pr;
  __syncthreads();
  if (t == 0) {
    float4 q0 = swred[0], q1 = swred[1];
    float BC = 0.f;
    for (int n = 0; n < 16; n++) BC += sB[n] * sC[n];
    float li0 = BC*(q0.x+q1.x) + iab[0], li1 = BC*(q0.y+q1.y) + iab[1];
    float lo0 = BC*(q0.z+q1.z) + oab[0], lo1 = BC*(q0.w+q1.w) + oab[1];
    uint32_t L0 = 2u*(uint32_t)b, L1 = L0 + 1u;
    inp[b]  = (li0 + gumbel32(ki0, ki1, L0) >= li1 + gumbel32(ki0, ki1, L1)) ? 1.0f : 0.0f;
    outp[b] = (lo0 + gumbel32(ko0, ko1, L0) >= lo1 + gumbel32(ko0, ko1, L1)) ? 1.0f : 0.0f;
  }
}

// ---------- fused spmm0 (rank-1 gather) + layer-1 update + deg1 + layer-2 self-term ----------
// flat0[v] = dw0*dxs[v](x)B[v] + sum_c coef0*dxs[c](x)B[c]
// state1[v] = E(x)flat0[v] + dxs[v](x)B[v],  E = exp(delta[v]*A)     (written iff inp[v]=1)
// dinv1[v] = rsqrt(outp[v]*sum_c inp[c] + 1)                          (written)
// y2p[v,d] = dinv1[v]^2 * <E*state1[v], C[v]>_n + dxs[v,d]*<B[v],C[v]>
__global__ __launch_bounds__(256) void k_spmm0f(
    const int* __restrict__ row_ptr, const int* __restrict__ csr_col,
    const float* __restrict__ dinv,
    const float* __restrict__ inp, const float* __restrict__ outp,
    const float* __restrict__ delta, const float* __restrict__ dxs,
    const float* __restrict__ Bm, const float* __restrict__ Cm,
    const float* __restrict__ Amat,
    float* __restrict__ s_out, float* __restrict__ dinv1,
    float* __restrict__ y2p) {
  int v = blockIdx.x, t = threadIdx.x;
  int d0 = t >> 2, d1 = d0 + 64, nb = t & 3;
  float dv = dinv[v];
  float4 Bv = ((const float4*)(Bm + ((size_t)v << 4)))[nb];
  float dx0 = dxs[v*128 + d0], dx1 = dxs[v*128 + d1];
  float dw = dv * dv;
  float c0 = dw * dx0, c1 = dw * dx1;
  float4 a0 = {c0*Bv.x, c0*Bv.y, c0*Bv.z, c0*Bv.w};
  float4 a1 = {c1*Bv.x, c1*Bv.y, c1*Bv.z, c1*Bv.w};
  float degs = 0.f;
  int j0 = row_ptr[v], j1 = row_ptr[v+1];
  for (int j = j0; j < j1; j++) {
    int c = csr_col[j];
    degs += inp[c];
    float coef = dv * dinv[c];
    float4 Bc = ((const float4*)(Bm + ((size_t)c << 4)))[nb];
    float e0 = coef * dxs[c*128 + d0];
    float e1 = coef * dxs[c*128 + d1];
    a0.x += e0*Bc.x; a0.y += e0*Bc.y; a0.z += e0*Bc.z; a0.w += e0*Bc.w;
    a1.x += e1*Bc.x; a1.y += e1*Bc.y; a1.z += e1*Bc.z; a1.w += e1*Bc.w;
  }
  float de0 = delta[v*128 + d0], de1 = delta[v*128 + d1];
  float4 A0 = ((const float4*)(Amat + (d0 << 4)))[nb];
  float4 A1 = ((const float4*)(Amat + (d1 << 4)))[nb];
  float4 E0, E1;
  E0.x = expf(de0*A0.x); E0.y = expf(de0*A0.y); E0.z = expf(de0*A0.z); E0.w = expf(de0*A0.w);
  E1.x = expf(de1*A1.x); E1.y = expf(de1*A1.y); E1.z = expf(de1*A1.z); E1.w = expf(de1*A1.w);
  float4 s0, s1;
  s0.x = E0.x*a0.x + dx0*Bv.x;  s0.y = E0.y*a0.y + dx0*Bv.y;
  s0.z = E0.z*a0.z + dx0*Bv.z;  s0.w = E0.w*a0.w + dx0*Bv.w;
  s1.x = E1.x*a1.x + dx1*Bv.x;  s1.y = E1.y*a1.y + dx1*Bv.y;
  s1.z = E1.z*a1.z + dx1*Bv.z;  s1.w = E1.w*a1.w + dx1*Bv.w;
  float gate_in = inp[v];
  if (gate_in != 0.f) {
    float4* op = (float4*)(s_out + ((size_t)v << 11));
    op[t] = s0; op[t + 256] = s1;
  }
  // dinv1 and layer-2 self-term
  float d1v = 1.0f / sqrtf(outp[v]*degs + 1.0f);
  if (t == 0) dinv1[v] = d1v;
  float dw1 = d1v * d1v;
  float4 Cv = ((const float4*)(Cm + ((size_t)v << 4)))[nb];
  float y0p = dw1*(E0.x*s0.x*Cv.x + E0.y*s0.y*Cv.y + E0.z*s0.z*Cv.z + E0.w*s0.w*Cv.w)
            + dx0*(Bv.x*Cv.x + Bv.y*Cv.y + Bv.z*Cv.z + Bv.w*Cv.w);
  float y1p = dw1*(E1.x*s1.x*Cv.x + E1.y*s1.y*Cv.y + E1.z*s1.z*Cv.z + E1.w*s1.w*Cv.w)
            + dx1*(Bv.x*Cv.x + Bv.y*Cv.y + Bv.z*Cv.z + Bv.w*Cv.w);
  y0p += __shfl_xor(y0p, 1); y0p += __shfl_xor(y0p, 2);
  y1p += __shfl_xor(y1p, 1); y1p += __shfl_xor(y1p, 2);
  if (nb == 0) {
    y2p[v*128 + d0] = y0p;
    y2p[v*128 + d1] = y1p;
  }
}

// ---------- fused gated spmm1 (gather-only) + layer-2 + output projection ----------
__global__ __launch_bounds__(256) void k_spmm1fo(
    const int* __restrict__ row_ptr, const int* __restrict__ csr_col,
    const float* __restrict__ dinv1,
    const float* __restrict__ inp, const float* __restrict__ outp,
    const float* __restrict__ delta,
    const float* __restrict__ Cm, const float* __restrict__ Amat,
    const float* __restrict__ s_in, const float* __restrict__ y2p,
    const float* __restrict__ xs, const float* __restrict__ rres,
    const float* __restrict__ Dv, const float* __restrict__ wout,
    float* __restrict__ out) {
  __shared__ float ty[128];
  int v = blockIdx.x, t = threadIdx.x;
  int d0 = t >> 2, d1 = d0 + 64, nb = t & 3;
  float4 a0 = {0.f,0.f,0.f,0.f}, a1 = {0.f,0.f,0.f,0.f};
  bool any = false;
  if (outp[v] != 0.f) {
    float dv = dinv1[v];
    int j0 = row_ptr[v], j1 = row_ptr[v+1];
    for (int j = j0; j < j1; j++) {
      int c = csr_col[j];
      if (inp[c] != 0.f) {
        any = true;
        float coef = dv * dinv1[c];
        const float4* nbp = (const float4*)(s_in + ((size_t)c << 11));
        float4 n0 = nbp[t], n1 = nbp[t + 256];
        a0.x += coef*n0.x; a0.y += coef*n0.y; a0.z += coef*n0.z; a0.w += coef*n0.w;
        a1.x += coef*n1.x; a1.y += coef*n1.y; a1.z += coef*n1.z; a1.w += coef*n1.w;
      }
    }
  }
  float y0g = 0.f, y1g = 0.f;
  if (any) {
    float de0 = delta[v*128 + d0], de1 = delta[v*128 + d1];
    float4 A0 = ((const float4*)(Amat + (d0 << 4)))[nb];
    float4 A1 = ((const float4*)(Amat + (d1 << 4)))[nb];
    float4 Cv = ((const float4*)(Cm + ((size_t)v << 4)))[nb];
    y0g = expf(de0*A0.x)*a0.x*Cv.x + expf(de0*A0.y)*a0.y*Cv.y +
          expf(de0*A0.z)*a0.z*Cv.z + expf(de0*A0.w)*a0.w*Cv.w;
    y1g = expf(de1*A1.x)*a1.x*Cv.x + expf(de1*A1.y)*a1.y*Cv.y +
          expf(de1*A1.z)*a1.z*Cv.z + expf(de1*A1.w)*a1.w*Cv.w;
  }
  y0g += __shfl_xor(y0g, 1); y0g += __shfl_xor(y0g, 2);
  y1g += __shfl_xor(y1g, 1); y1g += __shfl_xor(y1g, 2);
  if (nb == 0) {
    float yA = y0g + y2p[v*128 + d0];
    float yB = y1g + y2p[v*128 + d1];
    ty[d0] = (yA + xs[v*128 + d0]*Dv[d0]) * rres[v*128 + d0];
    ty[d1] = (yB + xs[v*128 + d1]*Dv[d1]) * rres[v*128 + d1];
  }
  __syncthreads();
  if (t < 64) {
    float acc = 0.f;
    for (int d = 0; d < 128; d++) acc += ty[d] * wout[d*64 + t];
    out[v*64 + t] = acc;
  }
}

extern "C" void kernel_launch(void* const* d_in, const int* in_sizes, int n_in,
                              void* d_out, int out_size, void* d_ws, size_t ws_size,
                              hipStream_t stream) {
  const float* x    = (const float*)d_in[0];
  const float* ipw  = (const float*)d_in[1];
  const float* xpw  = (const float*)d_in[2];
  const float* dtw  = (const float*)d_in[3];
  const float* alog = (const float*)d_in[4];
  const float* Dv   = (const float*)d_in[5];
  const float* wout = (const float*)d_in[6];
  const float* iaw  = (const float*)d_in[7];
  const float* iab  = (const float*)d_in[8];
  const float* oaw  = (const float*)d_in[9];
  const float* oab  = (const float*)d_in[10];
  const int*   ei   = (const int*)d_in[11];
  (void)in_sizes; (void)n_in; (void)out_size; (void)ws_size;

  float* W = (float*)d_ws;
  size_t o = 0;
  float* xs    = W + o; o += (size_t)NN*128;
  float* rres  = W + o; o += (size_t)NN*128;
  float* delta = W + o; o += (size_t)NN*128;
  float* dxs   = W + o; o += (size_t)NN*128;
  float* y2p   = W + o; o += (size_t)NN*128;
  float* Bm    = W + o; o += (size_t)NN*16;
  float* Cm    = W + o; o += (size_t)NN*16;
  float* Amat  = W + o; o += 2048;
  float* dinv0 = W + o; o += NN;
  float* dinv1 = W + o; o += NN;
  float* inp   = W + o; o += NN;
  float* outp  = W + o; o += NN;
  float* stA   = W + o; o += (size_t)NN*2048;   // state1 (rows with inp=1 only)
  int* row_ptr = (int*)(W + o);
  int* cnt     = row_ptr + (NN + 1);
  int* fill    = cnt + NN;
  int* csr_col = fill + NN;

  uint32_t ki0, ki1, ko0, ko1;
  tf2x32(0u, 42u, 0u, 0u, ki0, ki1);
  tf2x32(0u, 42u, 0u, 1u, ko0, ko1);

  // CSR build
  k_zero<<<(2*NN + 255)/256, 256, 0, stream>>>(cnt, 2*NN);
  k_count<<<NE/256, 256, 0, stream>>>(ei, cnt);
  k_scan<<<1, 1024, 0, stream>>>(cnt, row_ptr);
  k_scatter<<<NE/256, 256, 0, stream>>>(ei, row_ptr, fill, csr_col);
  k_dinv0<<<NN/256, 256, 0, stream>>>(row_ptr, dinv0);

  // per-node precompute + layer-0 gates
  k_prepA<<<8, 256, 0, stream>>>(alog, Amat);
  k_nodeprep<<<NN, 128, 0, stream>>>(x, ipw, xpw, dtw, iaw, iab, oaw, oab,
                                     ki0, ki1, ko0, ko1,
                                     xs, rres, delta, dxs, Bm, Cm, inp, outp);

  // spmm0 (rank-1) + layer-1 update + deg1 + layer-2 self-term -> state1(gated), dinv1, y2p
  k_spmm0f<<<NN, 256, 0, stream>>>(row_ptr, csr_col, dinv0, inp, outp,
                                   delta, dxs, Bm, Cm, Amat, stA, dinv1, y2p);

  // gated gather + layer-2 + output projection -> out
  k_spmm1fo<<<NN, 256, 0, stream>>>(row_ptr, csr_col, dinv1, inp, outp,
                                    delta, Cm, Amat, stA, y2p,
                                    xs, rres, Dv, wout, (float*)d_out);
}

// Round 4
// 186.473 us; speedup vs baseline: 2.1894x; 1.0465x over previous
//
#include <hip/hip_runtime.h>
#include <cstdint>

#define NN 8192
#define NE 65536
#define G 8   // nodes per block in nodeprep

typedef _Float16 h4 __attribute__((ext_vector_type(4)));

// ---------- Threefry-2x32, 20 rounds, JAX-compatible ----------
__host__ __device__ inline void tf2x32(uint32_t k0, uint32_t k1,
                                       uint32_t x0, uint32_t x1,
                                       uint32_t& r0, uint32_t& r1) {
  uint32_t ks2 = k0 ^ k1 ^ 0x1BD11BDAu;
  x0 += k0; x1 += k1;
#define TF_ROT(x,d) (((x)<<(d))|((x)>>(32-(d))))
#define TF_R4(ra,rb,rc,rd) \
  x0+=x1; x1=TF_ROT(x1,ra); x1^=x0; \
  x0+=x1; x1=TF_ROT(x1,rb); x1^=x0; \
  x0+=x1; x1=TF_ROT(x1,rc); x1^=x0; \
  x0+=x1; x1=TF_ROT(x1,rd); x1^=x0;
  TF_R4(13,15,26,6)  x0+=k1;  x1+=ks2+1u;
  TF_R4(17,29,16,24) x0+=ks2; x1+=k0+2u;
  TF_R4(13,15,26,6)  x0+=k0;  x1+=k1+3u;
  TF_R4(17,29,16,24) x0+=k1;  x1+=ks2+4u;
  TF_R4(13,15,26,6)  x0+=ks2; x1+=k0+5u;
  r0=x0; r1=x1;
#undef TF_R4
#undef TF_ROT
}

__device__ inline float gumbel32(uint32_t k0, uint32_t k1, uint32_t idx) {
  uint32_t a, b;
  tf2x32(k0, k1, 0u, idx, a, b);
  uint32_t bits = a ^ b;
  float f = __uint_as_float((bits >> 9) | 0x3f800000u) - 1.0f;
  float u = (f > 0.0f) ? f : 1.17549435e-38f;
  return -logf(-logf(u));
}

// ---------- CSR build ----------
__global__ void k_zero(int* __restrict__ p, int n) {
  int i = blockIdx.x*blockDim.x + threadIdx.x;
  if (i < n) p[i] = 0;
}

__global__ void k_count(const int* __restrict__ ei, int* __restrict__ cnt) {
  int e = blockIdx.x*blockDim.x + threadIdx.x;
  if (e < NE) atomicAdd(&cnt[ei[e]], 1);
}

// scan + dinv0 + Amat prep fused (single block)
__global__ __launch_bounds__(1024) void k_scan(const int* __restrict__ cnt,
                                               int* __restrict__ row_ptr,
                                               float* __restrict__ dinv0,
                                               const float* __restrict__ alog,
                                               float* __restrict__ Amat) {
  __shared__ int sums[1024];
  int t = threadIdx.x;
  Amat[t]        = -expf(alog[t]);
  Amat[t + 1024] = -expf(alog[t + 1024]);
  int base = t * 8;
  int loc[8]; int run = 0;
  for (int i = 0; i < 8; i++) {
    int c = cnt[base + i];
    dinv0[base + i] = 1.0f / sqrtf((float)(c + 1));
    loc[i] = run; run += c;
  }
  sums[t] = run; __syncthreads();
  for (int off = 1; off < 1024; off <<= 1) {
    int v = sums[t];
    int add = (t >= off) ? sums[t - off] : 0;
    __syncthreads();
    sums[t] = v + add;
    __syncthreads();
  }
  int prev = (t == 0) ? 0 : sums[t - 1];
  for (int i = 0; i < 8; i++) row_ptr[base + i] = prev + loc[i];
  if (t == 1023) row_ptr[NN] = sums[1023];
}

__global__ void k_scatter(const int* __restrict__ ei, const int* __restrict__ row_ptr,
                          int* __restrict__ fill, int* __restrict__ csr_col) {
  int e = blockIdx.x*blockDim.x + threadIdx.x;
  if (e < NE) {
    int v = ei[e];
    int pos = row_ptr[v] + atomicAdd(&fill[v], 1);
    csr_col[pos] = ei[NE + e];
  }
}

// ---------- per-node precompute + layer-0 gumbel gates, 8 nodes/block ----------
__global__ __launch_bounds__(256) void k_nodeprep(
    const float* __restrict__ x, const float* __restrict__ ipw,
    const float* __restrict__ xpw, const float* __restrict__ dtw,
    const float* __restrict__ iaw, const float* __restrict__ iab,
    const float* __restrict__ oaw, const float* __restrict__ oab,
    uint32_t ki0, uint32_t ki1, uint32_t ko0, uint32_t ko1,
    float* __restrict__ xs, float* __restrict__ rres,
    float* __restrict__ delta, float* __restrict__ dxs,
    float* __restrict__ Bm, float* __restrict__ Cm,
    float* __restrict__ inp, float* __restrict__ outp) {
  __shared__ float sx[G][64];
  __shared__ float sxs[G][128];
  __shared__ float sdbl[G][36];
  __shared__ float4 sred4[4];
  int t = threadIdx.x;
  int b0 = blockIdx.x * G;
  for (int i = t; i < G*64; i += 256) sx[i>>6][i&63] = x[b0*64 + i];
  __syncthreads();
  // GEMM1: [G x 64] @ [64 x 256]; each thread owns column t for all G nodes
  float acc[G];
#pragma unroll
  for (int g = 0; g < G; g++) acc[g] = 0.f;
  for (int k = 0; k < 64; k++) {
    float w = ipw[k*256 + t];
#pragma unroll
    for (int g = 0; g < G; g++) acc[g] += sx[g][k] * w;
  }
  if (t < 128) {
#pragma unroll
    for (int g = 0; g < G; g++) {
      float v = fmaxf(acc[g], 0.f);
      sxs[g][t] = v;
      xs[(size_t)(b0+g)*128 + t] = v;
    }
  } else {
    int j = t - 128;
#pragma unroll
    for (int g = 0; g < G; g++) rres[(size_t)(b0+g)*128 + j] = fmaxf(acc[g], 0.f);
  }
  __syncthreads();
  // GEMM2: x_dbl [G x 36] = sxs @ xpw
  for (int idx = t; idx < G*36; idx += 256) {
    int g = idx / 36, c = idx % 36;
    float a = 0.f;
    for (int d = 0; d < 128; d++) a += sxs[g][d] * xpw[d*36 + c];
    sdbl[g][c] = a;
    if (c >= 4 && c < 20)  Bm[(b0+g)*16 + (c-4)]  = a;
    else if (c >= 20)      Cm[(b0+g)*16 + (c-20)] = a;
  }
  __syncthreads();
  // GEMM3 + softplus + gates: threads 0-127 -> node hi*4+gg with hi=0, 128-255 -> hi=1
  int d = t & 127;
  int hi = t >> 7;
  int lane = t & 63, wv = t >> 6;
  for (int gg = 0; gg < 4; gg++) {
    int g = hi*4 + gg;
    int b = b0 + g;
    float dt = sdbl[g][0]*dtw[d]     + sdbl[g][1]*dtw[128+d]
             + sdbl[g][2]*dtw[256+d] + sdbl[g][3]*dtw[384+d];
    float dv = fmaxf(dt, 0.f) + log1pf(expf(-fabsf(dt)));  // softplus
    delta[(size_t)b*128 + d] = dv;
    float dxv = dv * sxs[g][d];
    dxs[(size_t)b*128 + d] = dxv;
    float4 pr;
    pr.x = dxv * iaw[2*d];   pr.y = dxv * iaw[2*d+1];
    pr.z = dxv * oaw[2*d];   pr.w = dxv * oaw[2*d+1];
    for (int off = 32; off >= 1; off >>= 1) {
      pr.x += __shfl_down(pr.x, off);
      pr.y += __shfl_down(pr.y, off);
      pr.z += __shfl_down(pr.z, off);
      pr.w += __shfl_down(pr.w, off);
    }
    if (lane == 0) sred4[wv] = pr;
    __syncthreads();
    if ((t & 127) == 0) {
      float4 q0 = sred4[hi*2], q1 = sred4[hi*2 + 1];
      float BC = 0.f;
      for (int n = 0; n < 16; n++) BC += sdbl[g][4+n] * sdbl[g][20+n];
      float li0 = BC*(q0.x+q1.x) + iab[0], li1 = BC*(q0.y+q1.y) + iab[1];
      float lo0 = BC*(q0.z+q1.z) + oab[0], lo1 = BC*(q0.w+q1.w) + oab[1];
      uint32_t L0 = 2u*(uint32_t)b, L1 = L0 + 1u;
      inp[b]  = (li0 + gumbel32(ki0, ki1, L0) >= li1 + gumbel32(ki0, ki1, L1)) ? 1.0f : 0.0f;
      outp[b] = (lo0 + gumbel32(ko0, ko1, L0) >= lo1 + gumbel32(ko0, ko1, L1)) ? 1.0f : 0.0f;
    }
    __syncthreads();
  }
}

// ---------- fused spmm0 (rank-1 gather) + layer-1 update + deg1 + layer-2 self-term ----------
// state1 stored fp16, only rows with inp[v]=1
__global__ __launch_bounds__(256) void k_spmm0f(
    const int* __restrict__ row_ptr, const int* __restrict__ csr_col,
    const float* __restrict__ dinv,
    const float* __restrict__ inp, const float* __restrict__ outp,
    const float* __restrict__ delta, const float* __restrict__ dxs,
    const float* __restrict__ Bm, const float* __restrict__ Cm,
    const float* __restrict__ Amat,
    _Float16* __restrict__ s_out, float* __restrict__ dinv1,
    float* __restrict__ y2p) {
  int v = blockIdx.x, t = threadIdx.x;
  int d0 = t >> 2, d1 = d0 + 64, nb = t & 3;
  float dv = dinv[v];
  float4 Bv = ((const float4*)(Bm + ((size_t)v << 4)))[nb];
  float dx0 = dxs[v*128 + d0], dx1 = dxs[v*128 + d1];
  float dw = dv * dv;
  float c0 = dw * dx0, c1 = dw * dx1;
  float4 a0 = {c0*Bv.x, c0*Bv.y, c0*Bv.z, c0*Bv.w};
  float4 a1 = {c1*Bv.x, c1*Bv.y, c1*Bv.z, c1*Bv.w};
  float degs = 0.f;
  int j0 = row_ptr[v], j1 = row_ptr[v+1];
  for (int j = j0; j < j1; j++) {
    int c = csr_col[j];
    degs += inp[c];
    float coef = dv * dinv[c];
    float4 Bc = ((const float4*)(Bm + ((size_t)c << 4)))[nb];
    float e0 = coef * dxs[c*128 + d0];
    float e1 = coef * dxs[c*128 + d1];
    a0.x += e0*Bc.x; a0.y += e0*Bc.y; a0.z += e0*Bc.z; a0.w += e0*Bc.w;
    a1.x += e1*Bc.x; a1.y += e1*Bc.y; a1.z += e1*Bc.z; a1.w += e1*Bc.w;
  }
  float de0 = delta[v*128 + d0], de1 = delta[v*128 + d1];
  float4 A0 = ((const float4*)(Amat + (d0 << 4)))[nb];
  float4 A1 = ((const float4*)(Amat + (d1 << 4)))[nb];
  float4 E0, E1;
  E0.x = expf(de0*A0.x); E0.y = expf(de0*A0.y); E0.z = expf(de0*A0.z); E0.w = expf(de0*A0.w);
  E1.x = expf(de1*A1.x); E1.y = expf(de1*A1.y); E1.z = expf(de1*A1.z); E1.w = expf(de1*A1.w);
  float4 s0, s1;
  s0.x = E0.x*a0.x + dx0*Bv.x;  s0.y = E0.y*a0.y + dx0*Bv.y;
  s0.z = E0.z*a0.z + dx0*Bv.z;  s0.w = E0.w*a0.w + dx0*Bv.w;
  s1.x = E1.x*a1.x + dx1*Bv.x;  s1.y = E1.y*a1.y + dx1*Bv.y;
  s1.z = E1.z*a1.z + dx1*Bv.z;  s1.w = E1.w*a1.w + dx1*Bv.w;
  if (inp[v] != 0.f) {
    h4* op = (h4*)(s_out + ((size_t)v << 11));
    h4 h0, h1;
    h0.x = (_Float16)s0.x; h0.y = (_Float16)s0.y; h0.z = (_Float16)s0.z; h0.w = (_Float16)s0.w;
    h1.x = (_Float16)s1.x; h1.y = (_Float16)s1.y; h1.z = (_Float16)s1.z; h1.w = (_Float16)s1.w;
    op[t] = h0; op[t + 256] = h1;
  }
  float d1v = 1.0f / sqrtf(outp[v]*degs + 1.0f);
  if (t == 0) dinv1[v] = d1v;
  float dw1 = d1v * d1v;
  float4 Cv = ((const float4*)(Cm + ((size_t)v << 4)))[nb];
  float y0p = dw1*(E0.x*s0.x*Cv.x + E0.y*s0.y*Cv.y + E0.z*s0.z*Cv.z + E0.w*s0.w*Cv.w)
            + dx0*(Bv.x*Cv.x + Bv.y*Cv.y + Bv.z*Cv.z + Bv.w*Cv.w);
  float y1p = dw1*(E1.x*s1.x*Cv.x + E1.y*s1.y*Cv.y + E1.z*s1.z*Cv.z + E1.w*s1.w*Cv.w)
            + dx1*(Bv.x*Cv.x + Bv.y*Cv.y + Bv.z*Cv.z + Bv.w*Cv.w);
  y0p += __shfl_xor(y0p, 1); y0p += __shfl_xor(y0p, 2);
  y1p += __shfl_xor(y1p, 1); y1p += __shfl_xor(y1p, 2);
  if (nb == 0) {
    y2p[v*128 + d0] = y0p;
    y2p[v*128 + d1] = y1p;
  }
}

// ---------- fused gated spmm1 (gather-only, fp16 state) + layer-2 + output projection ----------
__global__ __launch_bounds__(256) void k_spmm1fo(
    const int* __restrict__ row_ptr, const int* __restrict__ csr_col,
    const float* __restrict__ dinv1,
    const float* __restrict__ inp, const float* __restrict__ outp,
    const float* __restrict__ delta,
    const float* __restrict__ Cm, const float* __restrict__ Amat,
    const _Float16* __restrict__ s_in, const float* __restrict__ y2p,
    const float* __restrict__ xs, const float* __restrict__ rres,
    const float* __restrict__ Dv, const float* __restrict__ wout,
    float* __restrict__ out) {
  __shared__ float ty[128];
  int v = blockIdx.x, t = threadIdx.x;
  int d0 = t >> 2, d1 = d0 + 64, nb = t & 3;
  float4 a0 = {0.f,0.f,0.f,0.f}, a1 = {0.f,0.f,0.f,0.f};
  bool any = false;
  if (outp[v] != 0.f) {
    float dv = dinv1[v];
    int j0 = row_ptr[v], j1 = row_ptr[v+1];
    for (int j = j0; j < j1; j++) {
      int c = csr_col[j];
      if (inp[c] != 0.f) {
        any = true;
        float coef = dv * dinv1[c];
        const h4* nbp = (const h4*)(s_in + ((size_t)c << 11));
        h4 n0 = nbp[t], n1 = nbp[t + 256];
        a0.x += coef*(float)n0.x; a0.y += coef*(float)n0.y;
        a0.z += coef*(float)n0.z; a0.w += coef*(float)n0.w;
        a1.x += coef*(float)n1.x; a1.y += coef*(float)n1.y;
        a1.z += coef*(float)n1.z; a1.w += coef*(float)n1.w;
      }
    }
  }
  float y0g = 0.f, y1g = 0.f;
  if (any) {
    float de0 = delta[v*128 + d0], de1 = delta[v*128 + d1];
    float4 A0 = ((const float4*)(Amat + (d0 << 4)))[nb];
    float4 A1 = ((const float4*)(Amat + (d1 << 4)))[nb];
    float4 Cv = ((const float4*)(Cm + ((size_t)v << 4)))[nb];
    y0g = expf(de0*A0.x)*a0.x*Cv.x + expf(de0*A0.y)*a0.y*Cv.y +
          expf(de0*A0.z)*a0.z*Cv.z + expf(de0*A0.w)*a0.w*Cv.w;
    y1g = expf(de1*A1.x)*a1.x*Cv.x + expf(de1*A1.y)*a1.y*Cv.y +
          expf(de1*A1.z)*a1.z*Cv.z + expf(de1*A1.w)*a1.w*Cv.w;
  }
  y0g += __shfl_xor(y0g, 1); y0g += __shfl_xor(y0g, 2);
  y1g += __shfl_xor(y1g, 1); y1g += __shfl_xor(y1g, 2);
  if (nb == 0) {
    float yA = y0g + y2p[v*128 + d0];
    float yB = y1g + y2p[v*128 + d1];
    ty[d0] = (yA + xs[v*128 + d0]*Dv[d0]) * rres[v*128 + d0];
    ty[d1] = (yB + xs[v*128 + d1]*Dv[d1]) * rres[v*128 + d1];
  }
  __syncthreads();
  if (t < 64) {
    float acc = 0.f;
    for (int d = 0; d < 128; d++) acc += ty[d] * wout[d*64 + t];
    out[v*64 + t] = acc;
  }
}

extern "C" void kernel_launch(void* const* d_in, const int* in_sizes, int n_in,
                              void* d_out, int out_size, void* d_ws, size_t ws_size,
                              hipStream_t stream) {
  const float* x    = (const float*)d_in[0];
  const float* ipw  = (const float*)d_in[1];
  const float* xpw  = (const float*)d_in[2];
  const float* dtw  = (const float*)d_in[3];
  const float* alog = (const float*)d_in[4];
  const float* Dv   = (const float*)d_in[5];
  const float* wout = (const float*)d_in[6];
  const float* iaw  = (const float*)d_in[7];
  const float* iab  = (const float*)d_in[8];
  const float* oaw  = (const float*)d_in[9];
  const float* oab  = (const float*)d_in[10];
  const int*   ei   = (const int*)d_in[11];
  (void)in_sizes; (void)n_in; (void)out_size; (void)ws_size;

  float* W = (float*)d_ws;
  size_t o = 0;
  float* xs    = W + o; o += (size_t)NN*128;
  float* rres  = W + o; o += (size_t)NN*128;
  float* delta = W + o; o += (size_t)NN*128;
  float* dxs   = W + o; o += (size_t)NN*128;
  float* y2p   = W + o; o += (size_t)NN*128;
  float* Bm    = W + o; o += (size_t)NN*16;
  float* Cm    = W + o; o += (size_t)NN*16;
  float* Amat  = W + o; o += 2048;
  float* dinv0 = W + o; o += NN;
  float* dinv1 = W + o; o += NN;
  float* inp   = W + o; o += NN;
  float* outp  = W + o; o += NN;
  _Float16* stA = (_Float16*)(W + o); o += (size_t)NN*1024;  // fp16 state1, 32 MB
  int* row_ptr = (int*)(W + o);
  int* cnt     = row_ptr + (NN + 1);
  int* fill    = cnt + NN;
  int* csr_col = fill + NN;

  uint32_t ki0, ki1, ko0, ko1;
  tf2x32(0u, 42u, 0u, 0u, ki0, ki1);
  tf2x32(0u, 42u, 0u, 1u, ko0, ko1);

  // CSR build (+ dinv0 + Amat fused into scan)
  k_zero<<<(2*NN + 255)/256, 256, 0, stream>>>(cnt, 2*NN);
  k_count<<<NE/256, 256, 0, stream>>>(ei, cnt);
  k_scan<<<1, 1024, 0, stream>>>(cnt, row_ptr, dinv0, alog, Amat);
  k_scatter<<<NE/256, 256, 0, stream>>>(ei, row_ptr, fill, csr_col);

  // per-node precompute + layer-0 gates (8 nodes/block)
  k_nodeprep<<<NN/G, 256, 0, stream>>>(x, ipw, xpw, dtw, iaw, iab, oaw, oab,
                                       ki0, ki1, ko0, ko1,
                                       xs, rres, delta, dxs, Bm, Cm, inp, outp);

  // spmm0 (rank-1) + layer-1 update + deg1 + layer-2 self-term -> state1(fp16,gated), dinv1, y2p
  k_spmm0f<<<NN, 256, 0, stream>>>(row_ptr, csr_col, dinv0, inp, outp,
                                   delta, dxs, Bm, Cm, Amat, stA, dinv1, y2p);

  // gated gather + layer-2 + output projection -> out
  k_spmm1fo<<<NN, 256, 0, stream>>>(row_ptr, csr_col, dinv1, inp, outp,
                                    delta, Cm, Amat, stA, y2p,
                                    xs, rres, Dv, wout, (float*)d_out);
}

// Round 5
// 174.275 us; speedup vs baseline: 2.3426x; 1.0700x over previous
//
#include <hip/hip_runtime.h>
#include <cstdint>

#define NN 8192
#define NE 65536
#define G 8     // nodes per block in nodeprep
#define CAP 64  // bucket capacity per CSR row (Poisson λ=8 -> P(deg>64) ~ 0)

typedef _Float16 h4 __attribute__((ext_vector_type(4)));

// ---------- Threefry-2x32, 20 rounds, JAX-compatible ----------
__host__ __device__ inline void tf2x32(uint32_t k0, uint32_t k1,
                                       uint32_t x0, uint32_t x1,
                                       uint32_t& r0, uint32_t& r1) {
  uint32_t ks2 = k0 ^ k1 ^ 0x1BD11BDAu;
  x0 += k0; x1 += k1;
#define TF_ROT(x,d) (((x)<<(d))|((x)>>(32-(d))))
#define TF_R4(ra,rb,rc,rd) \
  x0+=x1; x1=TF_ROT(x1,ra); x1^=x0; \
  x0+=x1; x1=TF_ROT(x1,rb); x1^=x0; \
  x0+=x1; x1=TF_ROT(x1,rc); x1^=x0; \
  x0+=x1; x1=TF_ROT(x1,rd); x1^=x0;
  TF_R4(13,15,26,6)  x0+=k1;  x1+=ks2+1u;
  TF_R4(17,29,16,24) x0+=ks2; x1+=k0+2u;
  TF_R4(13,15,26,6)  x0+=k0;  x1+=k1+3u;
  TF_R4(17,29,16,24) x0+=k1;  x1+=ks2+4u;
  TF_R4(13,15,26,6)  x0+=ks2; x1+=k0+5u;
  r0=x0; r1=x1;
#undef TF_R4
#undef TF_ROT
}

__device__ inline float gumbel32(uint32_t k0, uint32_t k1, uint32_t idx) {
  uint32_t a, b;
  tf2x32(k0, k1, 0u, idx, a, b);
  uint32_t bits = a ^ b;
  float f = __uint_as_float((bits >> 9) | 0x3f800000u) - 1.0f;
  float u = (f > 0.0f) ? f : 1.17549435e-38f;
  return -logf(-logf(u));
}

// ---------- CSR build (bucketed: count + place in one pass) ----------
__global__ void k_zero(int* __restrict__ p, int n) {
  int i = blockIdx.x*blockDim.x + threadIdx.x;
  if (i < n) p[i] = 0;
}

__global__ void k_scatter(const int* __restrict__ ei, int* __restrict__ cnt,
                          int* __restrict__ csr_col) {
  int e = blockIdx.x*blockDim.x + threadIdx.x;
  if (e < NE) {
    int v = ei[e];
    int pos = atomicAdd(&cnt[v], 1);
    if (pos < CAP) csr_col[(v<<6) + pos] = ei[NE + e];
  }
}

// ---------- per-node precompute + layer-0 gumbel gates (8 nodes/block) ----------
// also: dinv0 from cnt; block 0 preps Amat = -exp(A_log)
__global__ __launch_bounds__(256) void k_nodeprep(
    const float* __restrict__ x, const float* __restrict__ ipw,
    const float* __restrict__ xpw, const float* __restrict__ dtw,
    const float* __restrict__ iaw, const float* __restrict__ iab,
    const float* __restrict__ oaw, const float* __restrict__ oab,
    const int* __restrict__ cnt, const float* __restrict__ alog,
    uint32_t ki0, uint32_t ki1, uint32_t ko0, uint32_t ko1,
    float* __restrict__ xs, float* __restrict__ rres,
    float* __restrict__ delta, float* __restrict__ dxs,
    float* __restrict__ Bm, float* __restrict__ Cm,
    float* __restrict__ inp, float* __restrict__ outp,
    float* __restrict__ dinv0, float* __restrict__ Amat) {
  __shared__ float sx[G][64];
  __shared__ float sxs[G][128];
  __shared__ float sdbl[G][36];
  __shared__ float4 sred4[4];
  int t = threadIdx.x;
  int b0 = blockIdx.x * G;
  if (blockIdx.x == 0) {
    for (int i = t; i < 2048; i += 256) Amat[i] = -expf(alog[i]);
  }
  if (t < G) {
    int v = b0 + t;
    dinv0[v] = 1.0f / sqrtf((float)(min(cnt[v], CAP)) + 1.0f);
  }
  for (int i = t; i < G*64; i += 256) sx[i>>6][i&63] = x[b0*64 + i];
  __syncthreads();
  // GEMM1: [G x 64] @ [64 x 256]
  float acc[G];
#pragma unroll
  for (int g = 0; g < G; g++) acc[g] = 0.f;
  for (int k = 0; k < 64; k++) {
    float w = ipw[k*256 + t];
#pragma unroll
    for (int g = 0; g < G; g++) acc[g] += sx[g][k] * w;
  }
  if (t < 128) {
#pragma unroll
    for (int g = 0; g < G; g++) {
      float v = fmaxf(acc[g], 0.f);
      sxs[g][t] = v;
      xs[(size_t)(b0+g)*128 + t] = v;
    }
  } else {
    int j = t - 128;
#pragma unroll
    for (int g = 0; g < G; g++) rres[(size_t)(b0+g)*128 + j] = fmaxf(acc[g], 0.f);
  }
  __syncthreads();
  // GEMM2: x_dbl [G x 36]
  for (int idx = t; idx < G*36; idx += 256) {
    int g = idx / 36, c = idx % 36;
    float a = 0.f;
    for (int d = 0; d < 128; d++) a += sxs[g][d] * xpw[d*36 + c];
    sdbl[g][c] = a;
    if (c >= 4 && c < 20)  Bm[(b0+g)*16 + (c-4)]  = a;
    else if (c >= 20)      Cm[(b0+g)*16 + (c-20)] = a;
  }
  __syncthreads();
  // GEMM3 + softplus + gates
  int d = t & 127;
  int hi = t >> 7;
  int lane = t & 63, wv = t >> 6;
  for (int gg = 0; gg < 4; gg++) {
    int g = hi*4 + gg;
    int b = b0 + g;
    float dt = sdbl[g][0]*dtw[d]     + sdbl[g][1]*dtw[128+d]
             + sdbl[g][2]*dtw[256+d] + sdbl[g][3]*dtw[384+d];
    float dv = fmaxf(dt, 0.f) + log1pf(expf(-fabsf(dt)));  // softplus
    delta[(size_t)b*128 + d] = dv;
    float dxv = dv * sxs[g][d];
    dxs[(size_t)b*128 + d] = dxv;
    float4 pr;
    pr.x = dxv * iaw[2*d];   pr.y = dxv * iaw[2*d+1];
    pr.z = dxv * oaw[2*d];   pr.w = dxv * oaw[2*d+1];
    for (int off = 32; off >= 1; off >>= 1) {
      pr.x += __shfl_down(pr.x, off);
      pr.y += __shfl_down(pr.y, off);
      pr.z += __shfl_down(pr.z, off);
      pr.w += __shfl_down(pr.w, off);
    }
    if (lane == 0) sred4[wv] = pr;
    __syncthreads();
    if ((t & 127) == 0) {
      float4 q0 = sred4[hi*2], q1 = sred4[hi*2 + 1];
      float BC = 0.f;
      for (int n = 0; n < 16; n++) BC += sdbl[g][4+n] * sdbl[g][20+n];
      float li0 = BC*(q0.x+q1.x) + iab[0], li1 = BC*(q0.y+q1.y) + iab[1];
      float lo0 = BC*(q0.z+q1.z) + oab[0], lo1 = BC*(q0.w+q1.w) + oab[1];
      uint32_t L0 = 2u*(uint32_t)b, L1 = L0 + 1u;
      inp[b]  = (li0 + gumbel32(ki0, ki1, L0) >= li1 + gumbel32(ki0, ki1, L1)) ? 1.0f : 0.0f;
      outp[b] = (lo0 + gumbel32(ko0, ko1, L0) >= lo1 + gumbel32(ko0, ko1, L1)) ? 1.0f : 0.0f;
    }
    __syncthreads();
  }
}

// ---------- fused spmm0 (rank-1 gather) + layer-1 update + deg1 + layer-2 self-term ----------
// neighbor list staged in LDS -> independent gather addresses (MLP)
__global__ __launch_bounds__(256) void k_spmm0f(
    const int* __restrict__ cnt, const int* __restrict__ csr_col,
    const float* __restrict__ dinv,
    const float* __restrict__ inp, const float* __restrict__ outp,
    const float* __restrict__ delta, const float* __restrict__ dxs,
    const float* __restrict__ Bm, const float* __restrict__ Cm,
    const float* __restrict__ Amat,
    _Float16* __restrict__ s_out, float* __restrict__ dinv1,
    float* __restrict__ y2p) {
  __shared__ int   sc[CAP];
  __shared__ float scoef[CAP];
  __shared__ float sgate[CAP];
  __shared__ float sdegs;
  int v = blockIdx.x, t = threadIdx.x;
  int deg = min(cnt[v], CAP);
  if (t < deg) {
    int c = csr_col[(v<<6) + t];
    sc[t] = c; scoef[t] = dinv[c]; sgate[t] = inp[c];
  }
  __syncthreads();
  if (t < 64) {
    float g = (t < deg) ? sgate[t] : 0.f;
    for (int off = 32; off >= 1; off >>= 1) g += __shfl_down(g, off);
    if (t == 0) sdegs = g;
  }
  int d0 = t >> 2, d1 = d0 + 64, nb = t & 3;
  float dv = dinv[v];
  float4 Bv = ((const float4*)(Bm + ((size_t)v << 4)))[nb];
  float dx0 = dxs[v*128 + d0], dx1 = dxs[v*128 + d1];
  float dw = dv * dv;
  float c0 = dw * dx0, c1 = dw * dx1;
  float4 a0 = {c0*Bv.x, c0*Bv.y, c0*Bv.z, c0*Bv.w};
  float4 a1 = {c1*Bv.x, c1*Bv.y, c1*Bv.z, c1*Bv.w};
  for (int j = 0; j < deg; j++) {
    int c = sc[j];
    float coef = dv * scoef[j];
    float4 Bc = ((const float4*)(Bm + ((size_t)c << 4)))[nb];
    float e0 = coef * dxs[c*128 + d0];
    float e1 = coef * dxs[c*128 + d1];
    a0.x += e0*Bc.x; a0.y += e0*Bc.y; a0.z += e0*Bc.z; a0.w += e0*Bc.w;
    a1.x += e1*Bc.x; a1.y += e1*Bc.y; a1.z += e1*Bc.z; a1.w += e1*Bc.w;
  }
  float de0 = delta[v*128 + d0], de1 = delta[v*128 + d1];
  float4 A0 = ((const float4*)(Amat + (d0 << 4)))[nb];
  float4 A1 = ((const float4*)(Amat + (d1 << 4)))[nb];
  float4 E0, E1;
  E0.x = expf(de0*A0.x); E0.y = expf(de0*A0.y); E0.z = expf(de0*A0.z); E0.w = expf(de0*A0.w);
  E1.x = expf(de1*A1.x); E1.y = expf(de1*A1.y); E1.z = expf(de1*A1.z); E1.w = expf(de1*A1.w);
  float4 s0, s1;
  s0.x = E0.x*a0.x + dx0*Bv.x;  s0.y = E0.y*a0.y + dx0*Bv.y;
  s0.z = E0.z*a0.z + dx0*Bv.z;  s0.w = E0.w*a0.w + dx0*Bv.w;
  s1.x = E1.x*a1.x + dx1*Bv.x;  s1.y = E1.y*a1.y + dx1*Bv.y;
  s1.z = E1.z*a1.z + dx1*Bv.z;  s1.w = E1.w*a1.w + dx1*Bv.w;
  if (inp[v] != 0.f) {
    h4* op = (h4*)(s_out + ((size_t)v << 11));
    h4 h0, h1;
    h0.x = (_Float16)s0.x; h0.y = (_Float16)s0.y; h0.z = (_Float16)s0.z; h0.w = (_Float16)s0.w;
    h1.x = (_Float16)s1.x; h1.y = (_Float16)s1.y; h1.z = (_Float16)s1.z; h1.w = (_Float16)s1.w;
    op[t] = h0; op[t + 256] = h1;
  }
  __syncthreads();
  float degs = sdegs;
  float d1v = 1.0f / sqrtf(outp[v]*degs + 1.0f);
  if (t == 0) dinv1[v] = d1v;
  float dw1 = d1v * d1v;
  float4 Cv = ((const float4*)(Cm + ((size_t)v << 4)))[nb];
  float y0p = dw1*(E0.x*s0.x*Cv.x + E0.y*s0.y*Cv.y + E0.z*s0.z*Cv.z + E0.w*s0.w*Cv.w)
            + dx0*(Bv.x*Cv.x + Bv.y*Cv.y + Bv.z*Cv.z + Bv.w*Cv.w);
  float y1p = dw1*(E1.x*s1.x*Cv.x + E1.y*s1.y*Cv.y + E1.z*s1.z*Cv.z + E1.w*s1.w*Cv.w)
            + dx1*(Bv.x*Cv.x + Bv.y*Cv.y + Bv.z*Cv.z + Bv.w*Cv.w);
  y0p += __shfl_xor(y0p, 1); y0p += __shfl_xor(y0p, 2);
  y1p += __shfl_xor(y1p, 1); y1p += __shfl_xor(y1p, 2);
  if (nb == 0) {
    y2p[v*128 + d0] = y0p;
    y2p[v*128 + d1] = y1p;
  }
}

// ---------- fused gated spmm1 + layer-2 + output projection ----------
// gated neighbors compacted in LDS -> dense loop of independent fp16 gathers
__global__ __launch_bounds__(256) void k_spmm1fo(
    const int* __restrict__ cnt, const int* __restrict__ csr_col,
    const float* __restrict__ dinv1,
    const float* __restrict__ inp, const float* __restrict__ outp,
    const float* __restrict__ delta,
    const float* __restrict__ Cm, const float* __restrict__ Amat,
    const _Float16* __restrict__ s_in, const float* __restrict__ y2p,
    const float* __restrict__ xs, const float* __restrict__ rres,
    const float* __restrict__ Dv, const float* __restrict__ wout,
    float* __restrict__ out) {
  __shared__ int   sc[CAP];
  __shared__ float scoef[CAP];
  __shared__ int   snact;
  __shared__ float ty[128];
  int v = blockIdx.x, t = threadIdx.x;
  if (t == 0) snact = 0;
  __syncthreads();
  int deg = (outp[v] != 0.f) ? min(cnt[v], CAP) : 0;
  if (t < deg) {
    int c = csr_col[(v<<6) + t];
    if (inp[c] != 0.f) {
      int p = atomicAdd(&snact, 1);
      sc[p] = c; scoef[p] = dinv1[c];
    }
  }
  __syncthreads();
  int nact = snact;
  int d0 = t >> 2, d1 = d0 + 64, nb = t & 3;
  float dv = dinv1[v];
  float4 a0 = {0.f,0.f,0.f,0.f}, a1 = {0.f,0.f,0.f,0.f};
  for (int j = 0; j < nact; j++) {
    int c = sc[j];
    float coef = dv * scoef[j];
    const h4* nbp = (const h4*)(s_in + ((size_t)c << 11));
    h4 n0 = nbp[t], n1 = nbp[t + 256];
    a0.x += coef*(float)n0.x; a0.y += coef*(float)n0.y;
    a0.z += coef*(float)n0.z; a0.w += coef*(float)n0.w;
    a1.x += coef*(float)n1.x; a1.y += coef*(float)n1.y;
    a1.z += coef*(float)n1.z; a1.w += coef*(float)n1.w;
  }
  float y0g = 0.f, y1g = 0.f;
  if (nact > 0) {
    float de0 = delta[v*128 + d0], de1 = delta[v*128 + d1];
    float4 A0 = ((const float4*)(Amat + (d0 << 4)))[nb];
    float4 A1 = ((const float4*)(Amat + (d1 << 4)))[nb];
    float4 Cv = ((const float4*)(Cm + ((size_t)v << 4)))[nb];
    y0g = expf(de0*A0.x)*a0.x*Cv.x + expf(de0*A0.y)*a0.y*Cv.y +
          expf(de0*A0.z)*a0.z*Cv.z + expf(de0*A0.w)*a0.w*Cv.w;
    y1g = expf(de1*A1.x)*a1.x*Cv.x + expf(de1*A1.y)*a1.y*Cv.y +
          expf(de1*A1.z)*a1.z*Cv.z + expf(de1*A1.w)*a1.w*Cv.w;
  }
  y0g += __shfl_xor(y0g, 1); y0g += __shfl_xor(y0g, 2);
  y1g += __shfl_xor(y1g, 1); y1g += __shfl_xor(y1g, 2);
  if (nb == 0) {
    float yA = y0g + y2p[v*128 + d0];
    float yB = y1g + y2p[v*128 + d1];
    ty[d0] = (yA + xs[v*128 + d0]*Dv[d0]) * rres[v*128 + d0];
    ty[d1] = (yB + xs[v*128 + d1]*Dv[d1]) * rres[v*128 + d1];
  }
  __syncthreads();
  if (t < 64) {
    float acc = 0.f;
    for (int d = 0; d < 128; d++) acc += ty[d] * wout[d*64 + t];
    out[v*64 + t] = acc;
  }
}

extern "C" void kernel_launch(void* const* d_in, const int* in_sizes, int n_in,
                              void* d_out, int out_size, void* d_ws, size_t ws_size,
                              hipStream_t stream) {
  const float* x    = (const float*)d_in[0];
  const float* ipw  = (const float*)d_in[1];
  const float* xpw  = (const float*)d_in[2];
  const float* dtw  = (const float*)d_in[3];
  const float* alog = (const float*)d_in[4];
  const float* Dv   = (const float*)d_in[5];
  const float* wout = (const float*)d_in[6];
  const float* iaw  = (const float*)d_in[7];
  const float* iab  = (const float*)d_in[8];
  const float* oaw  = (const float*)d_in[9];
  const float* oab  = (const float*)d_in[10];
  const int*   ei   = (const int*)d_in[11];
  (void)in_sizes; (void)n_in; (void)out_size; (void)ws_size;

  float* W = (float*)d_ws;
  size_t o = 0;
  float* xs    = W + o; o += (size_t)NN*128;
  float* rres  = W + o; o += (size_t)NN*128;
  float* delta = W + o; o += (size_t)NN*128;
  float* dxs   = W + o; o += (size_t)NN*128;
  float* y2p   = W + o; o += (size_t)NN*128;
  float* Bm    = W + o; o += (size_t)NN*16;
  float* Cm    = W + o; o += (size_t)NN*16;
  float* Amat  = W + o; o += 2048;
  float* dinv0 = W + o; o += NN;
  float* dinv1 = W + o; o += NN;
  float* inp   = W + o; o += NN;
  float* outp  = W + o; o += NN;
  _Float16* stA = (_Float16*)(W + o); o += (size_t)NN*1024;  // fp16 state1, 32 MB
  int* cnt     = (int*)(W + o);
  int* csr_col = cnt + NN;

  uint32_t ki0, ki1, ko0, ko1;
  tf2x32(0u, 42u, 0u, 0u, ki0, ki1);
  tf2x32(0u, 42u, 0u, 1u, ko0, ko1);

  // CSR build: zero counters, then bucket-scatter (count + place in one pass)
  k_zero<<<NN/256, 256, 0, stream>>>(cnt, NN);
  k_scatter<<<NE/256, 256, 0, stream>>>(ei, cnt, csr_col);

  // per-node precompute + layer-0 gates + dinv0 + Amat
  k_nodeprep<<<NN/G, 256, 0, stream>>>(x, ipw, xpw, dtw, iaw, iab, oaw, oab,
                                       cnt, alog, ki0, ki1, ko0, ko1,
                                       xs, rres, delta, dxs, Bm, Cm, inp, outp,
                                       dinv0, Amat);

  // spmm0 (rank-1) + layer-1 update + deg1 + layer-2 self-term
  k_spmm0f<<<NN, 256, 0, stream>>>(cnt, csr_col, dinv0, inp, outp,
                                   delta, dxs, Bm, Cm, Amat, stA, dinv1, y2p);

  // gated gather + layer-2 + output projection
  k_spmm1fo<<<NN, 256, 0, stream>>>(cnt, csr_col, dinv1, inp, outp,
                                    delta, Cm, Amat, stA, y2p,
                                    xs, rres, Dv, wout, (float*)d_out);
}